// Round 1
// baseline (373.514 us; speedup 1.0000x reference)
//
#include <hip/hip_runtime.h>
#include <hip/hip_bf16.h>

#define T_SEQ 2048
#define DM    2048
#define NH    16
#define DH    128
#define NBH   32          // B * NH
#define MROWS 4096        // B * T

typedef __bf16 bf16x8 __attribute__((ext_vector_type(8)));
typedef __bf16 bf16x4 __attribute__((ext_vector_type(4)));
typedef float  f32x4  __attribute__((ext_vector_type(4)));

__device__ __forceinline__ void async_copy16(const void* g, void* l) {
  __builtin_amdgcn_global_load_lds((const __attribute__((address_space(1))) void*)g,
                                   (__attribute__((address_space(3))) void*)l, 16, 0, 0);
}

// ---------------- prep kernels ----------------

__global__ void cast_bf16_k(const float* __restrict__ x, __bf16* __restrict__ xb) {
  int i = (blockIdx.x * 256 + threadIdx.x) * 4;
  float4 v = *reinterpret_cast<const float4*>(x + i);
  bf16x4 o;
  o[0] = (__bf16)v.x; o[1] = (__bf16)v.y; o[2] = (__bf16)v.z; o[3] = (__bf16)v.w;
  *reinterpret_cast<bf16x4*>(xb + i) = o;
}

// W [K][N] f32 -> WT [N][K] bf16
__global__ void transpose_cast_w(const float* __restrict__ W, __bf16* __restrict__ WT,
                                 int K, int N) {
  __shared__ float tile[32][33];
  int n0 = blockIdx.x * 32, k0 = blockIdx.y * 32;
  int tx = threadIdx.x, ty = threadIdx.y;
  #pragma unroll
  for (int i = 0; i < 4; i++)
    tile[ty + i * 8][tx] = W[(size_t)(k0 + ty + i * 8) * N + n0 + tx];
  __syncthreads();
  #pragma unroll
  for (int i = 0; i < 4; i++)
    WT[(size_t)(n0 + ty + i * 8) * K + k0 + tx] = (__bf16)tile[tx][ty + i * 8];
}

// Vb [BH][T][D] bf16 -> Vtb [BH][D][T] bf16
__global__ void transpose_v(const __bf16* __restrict__ Vb, __bf16* __restrict__ Vtb) {
  __shared__ __bf16 tile[32][34];
  int t0 = blockIdx.x * 32, d0 = blockIdx.y * 32, bh = blockIdx.z;
  const __bf16* src = Vb + (size_t)bh * T_SEQ * DH;
  __bf16* dst = Vtb + (size_t)bh * DH * T_SEQ;
  int tx = threadIdx.x, ty = threadIdx.y;
  #pragma unroll
  for (int i = 0; i < 4; i++)
    tile[ty + i * 8][tx] = src[(size_t)(t0 + ty + i * 8) * DH + d0 + tx];
  __syncthreads();
  #pragma unroll
  for (int i = 0; i < 4; i++)
    dst[(size_t)(d0 + ty + i * 8) * T_SEQ + t0 + tx] = tile[tx][ty + i * 8];
}

// ---------------- GEMM (C = A * Bt^T), 128x128 tile, BK=32 ----------------

__device__ __forceinline__ void stage_gemm(const __bf16* g, int ldk, int k0,
                                           __bf16* lds, int tid) {
  const int wave = tid >> 6, lane = tid & 63;
  #pragma unroll
  for (int j = 0; j < 2; j++) {
    int off = j * 4096 + wave * 1024;               // LDS byte offset (wave-uniform)
    int r = (off >> 6) + (lane >> 2);               // tile row
    const char* gs = (const char*)(g + (size_t)r * ldk + k0) + ((lane & 3) << 4);
    async_copy16(gs, (char*)lds + off);
  }
}

template <int EPI>
__global__ __launch_bounds__(256, 2) void gemm_bt(
    const __bf16* __restrict__ A, const __bf16* __restrict__ Bt, int K,
    const float* __restrict__ bias,
    const float* __restrict__ fcos, const float* __restrict__ fsin,
    __bf16* __restrict__ Qb, __bf16* __restrict__ Kb, __bf16* __restrict__ Vb,
    float* __restrict__ kout, float* __restrict__ vout,
    float* __restrict__ outp) {
  __shared__ __bf16 As[2][4096];
  __shared__ __bf16 Bs[2][4096];
  const int tid = threadIdx.x, lane = tid & 63, wave = tid >> 6;
  const int hi = lane >> 4, lo = lane & 15;
  const int wm = (wave >> 1) * 64, wn = (wave & 1) * 64;
  const __bf16* Ab = A + (size_t)blockIdx.y * 128 * K;
  const __bf16* Bb = Bt + (size_t)blockIdx.x * 128 * K;
  f32x4 acc[4][4] = {};
  const int NK = K >> 5;
  stage_gemm(Ab, K, 0, As[0], tid);
  stage_gemm(Bb, K, 0, Bs[0], tid);
  for (int kt = 0; kt < NK; ++kt) {
    int cur = kt & 1;
    if (kt + 1 < NK) {
      stage_gemm(Ab, K, (kt + 1) << 5, As[cur ^ 1], tid);
      stage_gemm(Bb, K, (kt + 1) << 5, Bs[cur ^ 1], tid);
    }
    __syncthreads();   // drains vmcnt(0): current tile ready
    bf16x8 af[4], bfr[4];
    #pragma unroll
    for (int i = 0; i < 4; i++) {
      af[i]  = *reinterpret_cast<const bf16x8*>(&As[cur][(wm + i * 16 + lo) * 32 + (hi << 3)]);
      bfr[i] = *reinterpret_cast<const bf16x8*>(&Bs[cur][(wn + i * 16 + lo) * 32 + (hi << 3)]);
    }
    #pragma unroll
    for (int i = 0; i < 4; i++)
      #pragma unroll
      for (int j = 0; j < 4; j++)
        acc[i][j] = __builtin_amdgcn_mfma_f32_16x16x32_bf16(af[i], bfr[j], acc[i][j], 0, 0, 0);
    __syncthreads();   // done reading this buffer
  }
  // epilogue. C layout: row = hi*4 + r, col = lo  (verified m89/m91)
  #pragma unroll
  for (int j = 0; j < 4; j++) {
    int n = blockIdx.x * 128 + wn + j * 16 + lo;
    float bv = bias[n];
    if (EPI == 1) {
      int which = n >> 11, wn2 = n & 2047, h = wn2 >> 7, d = wn2 & 127, jj = d >> 1;
      #pragma unroll
      for (int i = 0; i < 4; i++) {
        #pragma unroll
        for (int r = 0; r < 4; r++) {
          int row = blockIdx.y * 128 + wm + i * 16 + hi * 4 + r;
          int b = row >> 11, t = row & 2047;
          float v = acc[i][j][r] + bv;
          float other = __shfl_xor(v, 1, 64);   // partner of the rope pair
          float res = v;
          if (which < 2) {
            float c = fcos[t * 64 + jj], s = fsin[t * 64 + jj];
            res = (d & 1) ? (other * s + v * c) : (v * c - other * s);
          }
          size_t idx = (((size_t)(b * NH + h)) * T_SEQ + t) * DH + d;
          if (which == 0) {
            Qb[idx] = (__bf16)res;
          } else if (which == 1) {
            Kb[idx] = (__bf16)res; kout[idx] = res;
          } else {
            Vb[idx] = (__bf16)res; vout[idx] = res;
          }
        }
      }
    } else {
      #pragma unroll
      for (int i = 0; i < 4; i++) {
        #pragma unroll
        for (int r = 0; r < 4; r++) {
          int row = blockIdx.y * 128 + wm + i * 16 + hi * 4 + r;
          outp[(size_t)row * DM + n] = acc[i][j][r] + bv;
        }
      }
    }
  }
}

// ---------------- flash attention ----------------
// LDS tiles are [128 rows][256B rows], chunk-swizzled: chunk' = chunk ^ (row&7).
// Staged via global_load_lds (linear dest) with inverse-swizzled global source.

__device__ __forceinline__ void stage_swz(const __bf16* g, int rstride,
                                          __bf16* lds, int tid) {
  const int wave = tid >> 6, lane = tid & 63;
  const char* gb = (const char*)g;
  char* lb = (char*)lds;
  #pragma unroll
  for (int j = 0; j < 8; j++) {
    int off = j * 4096 + wave * 1024;               // wave-uniform LDS base
    int r = (off >> 8) + (lane >> 4);
    int c = lane & 15;
    const char* gs = gb + (size_t)r * (rstride * 2) + ((c ^ (r & 7)) << 4);
    async_copy16(gs, lb + off);
  }
}

__device__ __forceinline__ bf16x8 lds_frag(const __bf16* base, int row, int chunk) {
  return *reinterpret_cast<const bf16x8*>(
      reinterpret_cast<const char*>(base) + row * 256 + ((chunk ^ (row & 7)) << 4));
}

__global__ __launch_bounds__(256, 1) void attn_fwd(
    const __bf16* __restrict__ Qb, const __bf16* __restrict__ Kb,
    const __bf16* __restrict__ Vtb, __bf16* __restrict__ att_out) {
  __shared__ __bf16 Qs[128 * 128];
  __shared__ __bf16 Ks[128 * 128];
  __shared__ __bf16 Vts[128 * 128];
  __shared__ __bf16 Ps[4 * 32 * 128];   // per-wave P tile [32 q][128 s]
  const int tid = threadIdx.x, lane = tid & 63, wave = tid >> 6;
  const int hi = lane >> 4, lo = lane & 15;
  const int bh = blockIdx.y, b = bh >> 4, h = bh & 15;
  const __bf16* Qg = Qb + (size_t)bh * T_SEQ * DH;
  const __bf16* Kg = Kb + (size_t)bh * T_SEQ * DH;
  const __bf16* Vg = Vtb + (size_t)bh * DH * T_SEQ;
  const float scale = 0.08838834764831845f;   // 1/sqrt(128)
  const float L2E = 1.4426950408889634f;

  for (int pass = 0; pass < 2; ++pass) {
    int qi = pass ? (15 - blockIdx.x) : blockIdx.x;
    int q0 = qi * 128;
    __syncthreads();                           // all waves done with prev pass LDS
    stage_swz(Qg + (size_t)q0 * DH, DH, Qs, tid);
    f32x4 oacc[8][2] = {};
    float m0 = -3e38f, m1 = -3e38f, l0 = 0.f, l1 = 0.f;
    const int qgl0 = q0 + wave * 32 + lo;
    const int qgl1 = qgl0 + 16;

    for (int kt = 0; kt <= qi; ++kt) {
      __syncthreads();                         // prev tile reads done (+Q staged drained below)
      stage_swz(Kg + (size_t)kt * 128 * DH, DH, Ks, tid);
      stage_swz(Vg + (size_t)kt * 128, T_SEQ, Vts, tid);
      __syncthreads();                         // drains vmcnt(0): K/V (and Q) ready

      // S^T = K · Q^T : A = K[s][d], B = Q^T[d][q]; C: row=s (hi*4+r), col=q (lo)
      f32x4 sacc[8][2] = {};
      #pragma unroll
      for (int ks = 0; ks < 4; ++ks) {
        bf16x8 bq0 = lds_frag(Qs, wave * 32 + lo, ks * 4 + hi);
        bf16x8 bq1 = lds_frag(Qs, wave * 32 + 16 + lo, ks * 4 + hi);
        #pragma unroll
        for (int sf = 0; sf < 8; ++sf) {
          bf16x8 ak = lds_frag(Ks, sf * 16 + lo, ks * 4 + hi);
          sacc[sf][0] = __builtin_amdgcn_mfma_f32_16x16x32_bf16(ak, bq0, sacc[sf][0], 0, 0, 0);
          sacc[sf][1] = __builtin_amdgcn_mfma_f32_16x16x32_bf16(ak, bq1, sacc[sf][1], 0, 0, 0);
        }
      }
      const bool diag = (kt == qi);
      #pragma unroll
      for (int qf = 0; qf < 2; ++qf) {
        const int qgl = qf ? qgl1 : qgl0;
        float mold = qf ? m1 : m0;
        float mx = -3e38f;
        #pragma unroll
        for (int sf = 0; sf < 8; ++sf)
          #pragma unroll
          for (int r = 0; r < 4; ++r) {
            float v = sacc[sf][qf][r] * scale;
            if (diag && (kt * 128 + sf * 16 + hi * 4 + r) > qgl) v = -3e38f;
            sacc[sf][qf][r] = v;
            mx = fmaxf(mx, v);
          }
        mx = fmaxf(mx, __shfl_xor(mx, 16, 64));
        mx = fmaxf(mx, __shfl_xor(mx, 32, 64));
        float mnew = fmaxf(mold, mx);
        float alpha = __builtin_exp2f((mold - mnew) * L2E);
        if (qf) m1 = mnew; else m0 = mnew;
        float rs = 0.f;
        #pragma unroll
        for (int sf = 0; sf < 8; ++sf)
          #pragma unroll
          for (int r = 0; r < 4; ++r) {
            float p = __builtin_exp2f((sacc[sf][qf][r] - mnew) * L2E);
            sacc[sf][qf][r] = p;
            rs += p;
          }
        rs += __shfl_xor(rs, 16, 64);
        rs += __shfl_xor(rs, 32, 64);
        if (qf) l1 = l1 * alpha + rs; else l0 = l0 * alpha + rs;
        #pragma unroll
        for (int df = 0; df < 8; ++df) {
          oacc[df][qf][0] *= alpha; oacc[df][qf][1] *= alpha;
          oacc[df][qf][2] *= alpha; oacc[df][qf][3] *= alpha;
        }
        // write P tile: lane's 4 vals are contiguous s at row q_loc -> one b64
        const int q_loc = qf * 16 + lo;
        #pragma unroll
        for (int sf = 0; sf < 8; ++sf) {
          bf16x4 pk;
          pk[0] = (__bf16)sacc[sf][qf][0]; pk[1] = (__bf16)sacc[sf][qf][1];
          pk[2] = (__bf16)sacc[sf][qf][2]; pk[3] = (__bf16)sacc[sf][qf][3];
          int cb = sf * 32 + hi * 8;
          int chunk = cb >> 4, rem = cb & 15;
          char* p = (char*)Ps + wave * 8192 + q_loc * 256 +
                    (((chunk ^ (q_loc & 7)) << 4) | rem);
          *reinterpret_cast<bf16x4*>(p) = pk;
        }
      }
      // PV: O^T += V^T · P^T : A = V^T[d][s] (Vts rows), B = P[q][s] rows
      const __bf16* Pw = Ps + wave * 4096;
      #pragma unroll
      for (int ks = 0; ks < 4; ++ks) {
        bf16x8 bp0 = lds_frag(Pw, lo, ks * 4 + hi);
        bf16x8 bp1 = lds_frag(Pw, 16 + lo, ks * 4 + hi);
        #pragma unroll
        for (int df = 0; df < 8; ++df) {
          bf16x8 av = lds_frag(Vts, df * 16 + lo, ks * 4 + hi);
          oacc[df][0] = __builtin_amdgcn_mfma_f32_16x16x32_bf16(av, bp0, oacc[df][0], 0, 0, 0);
          oacc[df][1] = __builtin_amdgcn_mfma_f32_16x16x32_bf16(av, bp1, oacc[df][1], 0, 0, 0);
        }
      }
    } // kt

    // epilogue: O^T lane holds d = df*16 + hi*4 + r, q = qf*16 + lo
    #pragma unroll
    for (int qf = 0; qf < 2; ++qf) {
      float inv = 1.0f / (qf ? l1 : l0);
      int qrow = b * T_SEQ + q0 + wave * 32 + qf * 16 + lo;
      #pragma unroll
      for (int df = 0; df < 8; ++df) {
        bf16x4 pk;
        pk[0] = (__bf16)(oacc[df][qf][0] * inv);
        pk[1] = (__bf16)(oacc[df][qf][1] * inv);
        pk[2] = (__bf16)(oacc[df][qf][2] * inv);
        pk[3] = (__bf16)(oacc[df][qf][3] * inv);
        int d = df * 16 + hi * 4;
        *reinterpret_cast<bf16x4*>(att_out + (size_t)qrow * DM + h * DH + d) = pk;
      }
    }
  } // pass
}

// ---------------- launch ----------------

extern "C" void kernel_launch(void* const* d_in, const int* in_sizes, int n_in,
                              void* d_out, int out_size, void* d_ws, size_t ws_size,
                              hipStream_t stream) {
  const float* x     = (const float*)d_in[0];
  // d_in[1] = causal mask: ignored (mask applied analytically)
  const float* fcos  = (const float*)d_in[2];
  const float* fsin  = (const float*)d_in[3];
  const float* Wqkv  = (const float*)d_in[4];
  const float* bqkv  = (const float*)d_in[5];
  const float* Wproj = (const float*)d_in[6];
  const float* bproj = (const float*)d_in[7];
  float* out  = (float*)d_out;
  float* kout = out + (size_t)8388608;
  float* vout = out + (size_t)16777216;

  char* ws = (char*)d_ws;
  __bf16* xb     = (__bf16*)(ws);                 // 16 MiB; reused as att_out later
  __bf16* WqkvT  = (__bf16*)(ws + 16777216);      // 24 MiB
  __bf16* WprojT = (__bf16*)(ws + 41943040);      // 8 MiB
  __bf16* Qb     = (__bf16*)(ws + 50331648);      // 16 MiB
  __bf16* Kb     = (__bf16*)(ws + 67108864);      // 16 MiB
  __bf16* Vb     = (__bf16*)(ws + 83886080);      // 16 MiB
  __bf16* Vtb    = (__bf16*)(ws + 100663296);     // 16 MiB  (total 112 MiB)
  __bf16* att    = xb;                            // alias: xb dead after gemm1

  cast_bf16_k<<<8192, 256, 0, stream>>>(x, xb);
  transpose_cast_w<<<dim3(192, 64), dim3(32, 8), 0, stream>>>(Wqkv, WqkvT, DM, 3 * DM);
  transpose_cast_w<<<dim3(64, 64), dim3(32, 8), 0, stream>>>(Wproj, WprojT, DM, DM);
  gemm_bt<1><<<dim3(48, 32), 256, 0, stream>>>(xb, WqkvT, DM, bqkv, fcos, fsin,
                                               Qb, Kb, Vb, kout, vout, nullptr);
  transpose_v<<<dim3(64, 4, NBH), dim3(32, 8), 0, stream>>>(Vb, Vtb);
  attn_fwd<<<dim3(8, NBH), 256, 0, stream>>>(Qb, Kb, Vtb, att);
  gemm_bt<0><<<dim3(16, 32), 256, 0, stream>>>(att, WprojT, DM, bproj, nullptr, nullptr,
                                               nullptr, nullptr, nullptr, nullptr, nullptr, out);
}